// Round 9
// baseline (1541.937 us; speedup 1.0000x reference)
//
#include <hip/hip_runtime.h>
#include <stdint.h>

// ---------------------------------------------------------------------------
// FloydBlock2: global-norm -> QKV GEMM -> pivotal attention (row+col streams)
// B=4, N=128, C=512, H=8, D=64, SCALE=6.25
// Dtype-adaptive (probe): fp32 or bf16 I/O. GEMM uses hi/lo bf16 splits.
// R5: counted-vmcnt BK=32 dbuf pipeline (128-tile). R7: v2 dense.
// R10: 1-D grid + verified XCD swizzle -> 187us/launch, total 1500us.
// R11: av2-into-s2 fusion: NEUTRAL (within noise) + absmax 0.031->0.047
//      (extra bf16 round). REVERTED per pre-declared rule.
// R12: delete k_v2t (pure 34MB/group data-movement kernel): k_av2 gathers
//      its 16KB v2d column-slice directly (128x128B full-line reads) and
//      transposes through LDS T[d][p ^ ((d>>3)<<3)] (XOR key is a multiple
//      of 8: keeps ds_read_b128 p-blocks contiguous; write banks 2-way-free).
//      v2d now owns the old v2T slot -> no S aliasing hazard.
// ---------------------------------------------------------------------------

typedef __attribute__((ext_vector_type(8))) short s8v;   // 8 x bf16 (4 VGPRs)
typedef __attribute__((ext_vector_type(4))) float f4v;   // MFMA accumulator

#define MFMA(a, b, c) __builtin_amdgcn_mfma_f32_16x16x32_bf16((a), (b), (c), 0, 0, 0)

__device__ __forceinline__ float bf2f(unsigned short u) {
  union { unsigned int i; float f; } v; v.i = ((unsigned int)u) << 16; return v.f;
}
__device__ __forceinline__ unsigned short f2bf(float f) {
  union { float f; unsigned int i; } v; v.f = f;
  unsigned int i = v.i;
  return (unsigned short)((i + 0x7fffu + ((i >> 16) & 1u)) >> 16);  // RNE
}

__device__ __forceinline__ void async_copy16(const void* g, void* l) {
  __builtin_amdgcn_global_load_lds(
      (const __attribute__((address_space(1))) unsigned int*)(uintptr_t)g,
      (__attribute__((address_space(3))) unsigned int*)(uintptr_t)l,
      16, 0, 0);
}

// ---------------------------------------------------------------------------
// 0) dtype probe
// ---------------------------------------------------------------------------
__global__ __launch_bounds__(256) void k_probe(const unsigned short* __restrict__ x,
                                               int* __restrict__ flag) {
  uint4 v = ((const uint4*)x)[threadIdx.x];
  unsigned int uu[4] = {v.x, v.y, v.z, v.w};
  int bad = 0;
#pragma unroll
  for (int u = 0; u < 4; ++u) {
    float a = bf2f((unsigned short)(uu[u] & 0xffffu));
    float b = bf2f((unsigned short)(uu[u] >> 16));
    if (!(fabsf(a) <= 1e4f)) bad = 1;
    if (!(fabsf(b) <= 1e4f)) bad = 1;
  }
  if (bad) atomicOr(flag, 1);
}

// ---------------------------------------------------------------------------
// 1) Global sum / sumsq over raw x
// ---------------------------------------------------------------------------
__global__ __launch_bounds__(256) void k_red(const void* __restrict__ xraw,
                                             const int* __restrict__ flag,
                                             double* __restrict__ dstats) {
  __shared__ float red[8];
  const int fm = flag[0];
  int t = threadIdx.x;
  size_t gid = (size_t)blockIdx.x * 256 + t;
  float s = 0.f, ss = 0.f;
  if (fm) {
    const float4* pf = (const float4*)xraw;
#pragma unroll 4
    for (int it = 0; it < 32; ++it) {
      size_t idx = gid + (size_t)it * 131072;
      float4 u1 = pf[2 * idx], u2 = pf[2 * idx + 1];
      float vals[8] = {u1.x, u1.y, u1.z, u1.w, u2.x, u2.y, u2.z, u2.w};
#pragma unroll
      for (int u = 0; u < 8; ++u) { s += vals[u]; ss += vals[u] * vals[u]; }
    }
  } else {
    const uint4* p = (const uint4*)xraw;
#pragma unroll 4
    for (int it = 0; it < 32; ++it) {
      uint4 v = p[gid + (size_t)it * 131072];
      unsigned int uu[4] = {v.x, v.y, v.z, v.w};
#pragma unroll
      for (int u = 0; u < 4; ++u) {
        float a = bf2f((unsigned short)(uu[u] & 0xffffu));
        float b = bf2f((unsigned short)(uu[u] >> 16));
        s += a + b;
        ss += a * a + b * b;
      }
    }
  }
#pragma unroll
  for (int d = 32; d >= 1; d >>= 1) {
    s += __shfl_down(s, d);
    ss += __shfl_down(ss, d);
  }
  int lane = t & 63, wave = t >> 6;
  if (lane == 0) { red[wave] = s; red[4 + wave] = ss; }
  __syncthreads();
  if (t == 0) {
    atomicAdd(&dstats[0], (double)(red[0] + red[1] + red[2] + red[3]));
    atomicAdd(&dstats[1], (double)(red[4] + red[5] + red[6] + red[7]));
  }
}

__global__ void k_stats(const double* __restrict__ dstats, float* __restrict__ fstats) {
  double M = 33554432.0;
  double mean = dstats[0] / M;
  double var = (dstats[1] - dstats[0] * dstats[0] / M) / (M - 1.0);  // ddof=1
  double istd = 1.0 / sqrt(var);
  fstats[0] = (float)istd;
  fstats[1] = (float)(-mean * istd);
}

__global__ __launch_bounds__(256) void k_colsum(const void* __restrict__ wraw,
                                                const int* __restrict__ flag,
                                                float* __restrict__ colsum) {
  const int fm = flag[0];
  int c = blockIdx.x * 256 + threadIdx.x;
  if (c >= 2560) return;
  float s = 0.f;
  if (fm) {
    const float* w = (const float*)wraw;
    for (int r = 0; r < 512; ++r) s += w[(size_t)r * 2560 + c];
  } else {
    const unsigned short* w = (const unsigned short*)wraw;
    for (int r = 0; r < 512; ++r) s += bf2f(w[(size_t)r * 2560 + c]);
  }
  colsum[c] = s;
}

// wT hi/lo [n][k] = split(w[k][n])  (2560 x 512)
__global__ __launch_bounds__(256) void k_wt(const void* __restrict__ wraw,
                                            const int* __restrict__ flag,
                                            unsigned short* __restrict__ wThi,
                                            unsigned short* __restrict__ wTlo) {
  __shared__ float tile[64][65];
  const int fm = flag[0];
  int n0 = blockIdx.x * 64, r0 = blockIdx.y * 64;
#pragma unroll
  for (int rep = 0; rep < 16; ++rep) {
    int idx = rep * 256 + threadIdx.x;
    int r = idx >> 6, n = idx & 63;
    float v;
    if (fm) v = ((const float*)wraw)[(size_t)(r0 + r) * 2560 + n0 + n];
    else    v = bf2f(((const unsigned short*)wraw)[(size_t)(r0 + r) * 2560 + n0 + n]);
    tile[r][n] = v;
  }
  __syncthreads();
#pragma unroll
  for (int rep = 0; rep < 16; ++rep) {
    int idx = rep * 256 + threadIdx.x;
    int n = idx >> 6, r = idx & 63;
    float v = tile[r][n];
    unsigned short hi = f2bf(v);
    size_t o = (size_t)(n0 + n) * 512 + r0 + r;
    wThi[o] = hi;
    wTlo[o] = f2bf(v - bf2f(hi));
  }
}

// per-b slice conversion: x[b] -> xhi/xlo bf16 [16384][512]
__global__ __launch_bounds__(256) void k_convx(const void* __restrict__ xraw,
                                               const int* __restrict__ flag,
                                               unsigned short* __restrict__ xhi,
                                               unsigned short* __restrict__ xlo,
                                               int b) {
  const int fm = flag[0];
  size_t e0 = ((size_t)blockIdx.x * 256 + threadIdx.x) * 8;
  size_t g0 = (size_t)b * 8388608 + e0;
  float vals[8];
  if (fm) {
    const float4* pf = (const float4*)xraw;
    float4 u1 = pf[g0 / 4], u2 = pf[g0 / 4 + 1];
    vals[0] = u1.x; vals[1] = u1.y; vals[2] = u1.z; vals[3] = u1.w;
    vals[4] = u2.x; vals[5] = u2.y; vals[6] = u2.z; vals[7] = u2.w;
  } else {
    uint4 v = ((const uint4*)xraw)[g0 / 8];
    unsigned int uu[4] = {v.x, v.y, v.z, v.w};
#pragma unroll
    for (int u = 0; u < 4; ++u) {
      vals[2 * u] = bf2f((unsigned short)(uu[u] & 0xffffu));
      vals[2 * u + 1] = bf2f((unsigned short)(uu[u] >> 16));
    }
  }
  unsigned short h[8], l[8];
#pragma unroll
  for (int u = 0; u < 8; ++u) {
    h[u] = f2bf(vals[u]);
    l[u] = f2bf(vals[u] - bf2f(h[u]));
  }
  *(uint4*)(xhi + e0) = *(const uint4*)h;
  *(uint4*)(xlo + e0) = *(const uint4*)l;
}

// ---------------------------------------------------------------------------
// 2) QKV GEMM, 128x128 tiles, BK=32 double-buffered, hi/lo 3-term MFMA.
//    Counted-vmcnt pipeline + verified XCD swizzle (R10).
// ---------------------------------------------------------------------------
__global__ __launch_bounds__(256) void k_gemm(
    const unsigned short* __restrict__ xhi, const unsigned short* __restrict__ xlo,
    const unsigned short* __restrict__ wThi, const unsigned short* __restrict__ wTlo,
    const float* __restrict__ colsum, const float* __restrict__ fstats,
    const int* __restrict__ flag,
    unsigned short* __restrict__ qhi, unsigned short* __restrict__ qlo,
    unsigned short* __restrict__ k1hi, unsigned short* __restrict__ k1lo,
    unsigned short* __restrict__ k2hi, unsigned short* __restrict__ k2lo,
    unsigned short* __restrict__ v1T, unsigned short* __restrict__ v2d,
    int h0, int hcShift, int nwgy) {
  __shared__ __align__(16) unsigned short Ash[2][4096];   // [buf][128 rows x 32 el]
  __shared__ __align__(16) unsigned short Asl[2][4096];
  __shared__ __align__(16) unsigned short Bsh[2][4096];
  __shared__ __align__(16) unsigned short Bsl[2][4096];
  const int fm = flag[0];
  const int t = threadIdx.x;

  // verified XCD mapping on 1-D grid (nwg = 128*nwgy, nwg%8==0).
  const int vid = blockIdx.x;
  const int xcd = vid & 7, seq = vid >> 3;
  const int m0 = (xcd * 16 + seq / nwgy) * 128;
  const int n0 = (seq % nwgy) * 128;

  const int hcMask = (1 << hcShift) - 1;

  const int lane = t & 63, wave = t >> 6;
  const int wm = (wave & 1) * 64, wn = (wave >> 1) * 64;
  const int l16 = lane & 15, q4 = lane >> 4;

  const int srow0 = t >> 2;
  const int srow1 = 64 + srow0;
  const int sch = (((t & 3) ^ ((t >> 3) & 3)) << 3);     // element offset in row
  const int swoff = ((q4 ^ ((l16 >> 1) & 3)) << 3);

  const float af = fstats[0], bfc = fstats[1];
  const unsigned short* xh = xhi + (size_t)m0 * 512;
  const unsigned short* xl = xlo + (size_t)m0 * 512;

  int wcol0, wcol1;
  {
    int n = n0 + srow0, g = n >> hcShift, rem = n & hcMask;
    wcol0 = (g << 9) + ((h0 + (rem >> 6)) << 6) + (rem & 63);
    n = n0 + srow1; g = n >> hcShift; rem = n & hcMask;
    wcol1 = (g << 9) + ((h0 + (rem >> 6)) << 6) + (rem & 63);
  }

  f4v acc[4][4];
#pragma unroll
  for (int a = 0; a < 4; ++a)
#pragma unroll
    for (int c = 0; c < 4; ++c) acc[a][c] = (f4v)0.f;

  auto STAGE = [&](int bsel, int k0) {
    async_copy16(xh + (size_t)srow0 * 512 + k0 + sch, (char*)&Ash[bsel][0] + t * 16);
    async_copy16(xh + (size_t)srow1 * 512 + k0 + sch, (char*)&Ash[bsel][0] + (256 + t) * 16);
    async_copy16(wThi + (size_t)wcol0 * 512 + k0 + sch, (char*)&Bsh[bsel][0] + t * 16);
    async_copy16(wThi + (size_t)wcol1 * 512 + k0 + sch, (char*)&Bsh[bsel][0] + (256 + t) * 16);
    if (fm) {
      async_copy16(xl + (size_t)srow0 * 512 + k0 + sch, (char*)&Asl[bsel][0] + t * 16);
      async_copy16(xl + (size_t)srow1 * 512 + k0 + sch, (char*)&Asl[bsel][0] + (256 + t) * 16);
      async_copy16(wTlo + (size_t)wcol0 * 512 + k0 + sch, (char*)&Bsl[bsel][0] + t * 16);
      async_copy16(wTlo + (size_t)wcol1 * 512 + k0 + sch, (char*)&Bsl[bsel][0] + (256 + t) * 16);
    }
  };

  STAGE(0, 0);

#pragma unroll 2
  for (int ks = 0; ks < 16; ++ks) {
    const int kb = ks & 1;
    if (ks < 15) {
      STAGE(kb ^ 1, (ks + 1) << 5);   // prefetch next tile (other buf)
      if (fm) asm volatile("s_waitcnt vmcnt(8)" ::: "memory");
      else    asm volatile("s_waitcnt vmcnt(4)" ::: "memory");
    } else {
      asm volatile("s_waitcnt vmcnt(0)" ::: "memory");  // epilogue drain
    }
    __builtin_amdgcn_s_barrier();     // all waves' buf[kb] loads landed

    s8v ah[4], bh[4];
#pragma unroll
    for (int jt = 0; jt < 4; ++jt)
      ah[jt] = *(const s8v*)&Ash[kb][(wm + jt * 16 + l16) * 32 + swoff];
#pragma unroll
    for (int nt = 0; nt < 4; ++nt)
      bh[nt] = *(const s8v*)&Bsh[kb][(wn + nt * 16 + l16) * 32 + swoff];
    if (fm) {
      s8v al[4], bl[4];
#pragma unroll
      for (int jt = 0; jt < 4; ++jt)
        al[jt] = *(const s8v*)&Asl[kb][(wm + jt * 16 + l16) * 32 + swoff];
#pragma unroll
      for (int nt = 0; nt < 4; ++nt)
        bl[nt] = *(const s8v*)&Bsl[kb][(wn + nt * 16 + l16) * 32 + swoff];
#pragma unroll
      for (int jt = 0; jt < 4; ++jt)
#pragma unroll
        for (int nt = 0; nt < 4; ++nt) {
          acc[jt][nt] = MFMA(ah[jt], bh[nt], acc[jt][nt]);
          acc[jt][nt] = MFMA(ah[jt], bl[nt], acc[jt][nt]);
          acc[jt][nt] = MFMA(al[jt], bh[nt], acc[jt][nt]);
        }
    } else {
#pragma unroll
      for (int jt = 0; jt < 4; ++jt)
#pragma unroll
        for (int nt = 0; nt < 4; ++nt) acc[jt][nt] = MFMA(ah[jt], bh[nt], acc[jt][nt]);
    }
    asm volatile("" ::: "memory");    // pin ds_reads above the barrier
    __builtin_amdgcn_s_barrier();     // buf[kb] free for ks+1's STAGE
  }

  // epilogue: affine + head-scatter  (C/D map: col=lane&15, row=q4*4+reg)
#pragma unroll
  for (int jt = 0; jt < 4; ++jt) {
#pragma unroll
    for (int nt = 0; nt < 4; ++nt) {
      int gcol = n0 + wn + nt * 16 + l16;
      int g = gcol >> hcShift, rem = gcol & hcMask;
      int hl = rem >> 6, d = rem & 63;
      int wcol = (g << 9) + ((h0 + hl) << 6) + d;
      float cs = colsum[wcol] * bfc;
#pragma unroll
      for (int r = 0; r < 4; ++r) {
        int grow = m0 + wm + jt * 16 + q4 * 4 + r;
        int i = grow >> 7, j = grow & 127;
        float val = acc[jt][nt][r] * af + cs;
        unsigned short hi = f2bf(val);
        if (g == 0) {
          size_t idx = (((size_t)hl * 128 + i) * 128 + j) * 64 + d;
          qhi[idx] = hi; qlo[idx] = f2bf(val - bf2f(hi));
        } else if (g == 1) {
          size_t idx = (((size_t)hl * 128 + i) * 128 + j) * 64 + d;
          k1hi[idx] = hi; k1lo[idx] = f2bf(val - bf2f(hi));
        } else if (g == 2) {
          size_t idx = (((size_t)hl * 128 + j) * 128 + i) * 64 + d;
          k2hi[idx] = hi; k2lo[idx] = f2bf(val - bf2f(hi));
        } else if (g == 3) {
          size_t idx = (((size_t)hl * 128 + i) * 64 + d) * 128 + j;
          v1T[idx] = hi;
        } else {
          // dense v2 [hl][p=i][j][d] -- full-line, single-block-owned.
          size_t idx = (((size_t)hl * 128 + i) * 128 + j) * 64 + d;
          v2d[idx] = hi;
        }
      }
    }
  }
}

// ---------------------------------------------------------------------------
// 3) S1[j,k] = sum_d q[i,j,d]*k1[i,k,d] per (hl, i)
// ---------------------------------------------------------------------------
__global__ __launch_bounds__(256) void k_s1(
    const unsigned short* __restrict__ qhi, const unsigned short* __restrict__ qlo,
    const unsigned short* __restrict__ k1hi, const unsigned short* __restrict__ k1lo,
    float* __restrict__ S) {
  const int i = blockIdx.x, hl = blockIdx.y;
  const int t = threadIdx.x, lane = t & 63, wave = t >> 6;
  const int l16 = lane & 15, q4 = lane >> 4;
  const size_t base = ((size_t)hl * 128 + i) * 128 * 64;

  f4v acc[2][8];
#pragma unroll
  for (int a = 0; a < 2; ++a)
#pragma unroll
    for (int c = 0; c < 8; ++c) acc[a][c] = (f4v)0.f;

#pragma unroll
  for (int kc = 0; kc < 2; ++kc) {
    s8v ah[2], al[2];
#pragma unroll
    for (int jt = 0; jt < 2; ++jt) {
      size_t off = base + (size_t)(wave * 32 + jt * 16 + l16) * 64 + kc * 32 + q4 * 8;
      ah[jt] = *(const s8v*)(qhi + off);
      al[jt] = *(const s8v*)(qlo + off);
    }
#pragma unroll
    for (int kt = 0; kt < 8; ++kt) {
      size_t off = base + (size_t)(kt * 16 + l16) * 64 + kc * 32 + q4 * 8;
      s8v bh = *(const s8v*)(k1hi + off);
      s8v bl = *(const s8v*)(k1lo + off);
#pragma unroll
      for (int jt = 0; jt < 2; ++jt) {
        acc[jt][kt] = MFMA(ah[jt], bh, acc[jt][kt]);
        acc[jt][kt] = MFMA(ah[jt], bl, acc[jt][kt]);
        acc[jt][kt] = MFMA(al[jt], bh, acc[jt][kt]);
      }
    }
  }
  float* Sb = S + ((size_t)hl * 128 + i) * 128 * 128;
#pragma unroll
  for (int jt = 0; jt < 2; ++jt)
#pragma unroll
    for (int kt = 0; kt < 8; ++kt)
#pragma unroll
      for (int r = 0; r < 4; ++r) {
        int j = wave * 32 + jt * 16 + q4 * 4 + r;
        Sb[(size_t)j * 128 + kt * 16 + l16] = acc[jt][kt][r];
      }
}

// ---------------------------------------------------------------------------
// 4) S2[i,k] per (hl, j); add S1, scale, softmax over k, write attn bf16
// ---------------------------------------------------------------------------
__global__ __launch_bounds__(256) void k_s2(
    const unsigned short* __restrict__ qhi, const unsigned short* __restrict__ qlo,
    const unsigned short* __restrict__ k2hi, const unsigned short* __restrict__ k2lo,
    const float* __restrict__ S, unsigned short* __restrict__ attn) {
  const int j = blockIdx.x, hl = blockIdx.y;
  const int t = threadIdx.x, lane = t & 63, wave = t >> 6;
  const int l16 = lane & 15, q4 = lane >> 4;
  const size_t bbase = ((size_t)hl * 128 + j) * 128 * 64;

  f4v acc[2][8];
#pragma unroll
  for (int a = 0; a < 2; ++a)
#pragma unroll
    for (int c = 0; c < 8; ++c) acc[a][c] = (f4v)0.f;

#pragma unroll
  for (int kc = 0; kc < 2; ++kc) {
    s8v ah[2], al[2];
#pragma unroll
    for (int it = 0; it < 2; ++it) {
      size_t off = (((size_t)hl * 128 + (wave * 32 + it * 16 + l16)) * 128 + j) * 64 +
                   kc * 32 + q4 * 8;
      ah[it] = *(const s8v*)(qhi + off);
      al[it] = *(const s8v*)(qlo + off);
    }
#pragma unroll
    for (int kt = 0; kt < 8; ++kt) {
      size_t off = bbase + (size_t)(kt * 16 + l16) * 64 + kc * 32 + q4 * 8;
      s8v bh = *(const s8v*)(k2hi + off);
      s8v bl = *(const s8v*)(k2lo + off);
#pragma unroll
      for (int it = 0; it < 2; ++it) {
        acc[it][kt] = MFMA(ah[it], bh, acc[it][kt]);
        acc[it][kt] = MFMA(ah[it], bl, acc[it][kt]);
        acc[it][kt] = MFMA(al[it], bh, acc[it][kt]);
      }
    }
  }

#pragma unroll
  for (int it = 0; it < 2; ++it) {
#pragma unroll
    for (int r = 0; r < 4; ++r) {
      int i = wave * 32 + it * 16 + q4 * 4 + r;
      const float* Srow = S + (((size_t)hl * 128 + i) * 128 + j) * 128;
      float tv[8];
      float m = -3.4e38f;
#pragma unroll
      for (int kt = 0; kt < 8; ++kt) {
        tv[kt] = 6.25f * (Srow[kt * 16 + l16] + acc[it][kt][r]);
        m = fmaxf(m, tv[kt]);
      }
#pragma unroll
      for (int d = 1; d <= 8; d <<= 1) m = fmaxf(m, __shfl_xor(m, d));
      float sum = 0.f;
#pragma unroll
      for (int kt = 0; kt < 8; ++kt) {
        tv[kt] = __expf(tv[kt] - m);
        sum += tv[kt];
      }
#pragma unroll
      for (int d = 1; d <= 8; d <<= 1) sum += __shfl_xor(sum, d);
      float rs = 1.f / sum;
      unsigned short* arow = attn + (((size_t)hl * 128 + i) * 128 + j) * 128;
#pragma unroll
      for (int kt = 0; kt < 8; ++kt) arow[kt * 16 + l16] = f2bf(tv[kt] * rs);
    }
  }
}

// ---------------------------------------------------------------------------
// 5) O1[j,d] = sum_k attn[i,j,k]*v1[i,k,d] per (hl, i); out1 bf16
// ---------------------------------------------------------------------------
__global__ __launch_bounds__(256) void k_av1(
    const unsigned short* __restrict__ attn, const unsigned short* __restrict__ v1T,
    unsigned short* __restrict__ out1) {
  const int i = blockIdx.x, hl = blockIdx.y;
  const int t = threadIdx.x, lane = t & 63, wave = t >> 6;
  const int l16 = lane & 15, q4 = lane >> 4;
  const size_t abase = ((size_t)hl * 128 + i) * 128 * 128;
  const size_t vbase = ((size_t)hl * 128 + i) * 64 * 128;

  f4v acc[2][4];
#pragma unroll
  for (int a = 0; a < 2; ++a)
#pragma unroll
    for (int c = 0; c < 4; ++c) acc[a][c] = (f4v)0.f;

#pragma unroll
  for (int kc = 0; kc < 4; ++kc) {
    s8v a[2], bfr[4];
#pragma unroll
    for (int jt = 0; jt < 2; ++jt)
      a[jt] = *(const s8v*)(attn + abase + (size_t)(wave * 32 + jt * 16 + l16) * 128 +
                            kc * 32 + q4 * 8);
#pragma unroll
    for (int dt = 0; dt < 4; ++dt)
      bfr[dt] = *(const s8v*)(v1T + vbase + (size_t)(dt * 16 + l16) * 128 + kc * 32 + q4 * 8);
#pragma unroll
    for (int jt = 0; jt < 2; ++jt)
#pragma unroll
      for (int dt = 0; dt < 4; ++dt) acc[jt][dt] = MFMA(a[jt], bfr[dt], acc[jt][dt]);
  }
  unsigned short* ob = out1 + ((size_t)hl * 128 + i) * 128 * 64;
#pragma unroll
  for (int jt = 0; jt < 2; ++jt)
#pragma unroll
    for (int dt = 0; dt < 4; ++dt)
#pragma unroll
      for (int r = 0; r < 4; ++r) {
        int j = wave * 32 + jt * 16 + q4 * 4 + r;
        ob[(size_t)j * 64 + dt * 16 + l16] = f2bf(acc[jt][dt][r]);
      }
}

// ---------------------------------------------------------------------------
// 6) R12: O2[i,d] per (hl, j): gather v2d[hl,:,j,:] (128 x 128B full-line
//    reads), transpose through LDS T[d][p ^ ((d>>3)<<3)], PV2 MFMA,
//    add out1, dtype-branched final store. (k_v2t deleted.)
// ---------------------------------------------------------------------------
__global__ __launch_bounds__(256) void k_av2(
    const unsigned short* __restrict__ attn, const unsigned short* __restrict__ v2d,
    const unsigned short* __restrict__ out1, const int* __restrict__ flag,
    void* __restrict__ out, int b, int h0) {
  __shared__ __align__(16) unsigned short T[64 * 136];   // [d][p^swz], 17.4KB
  const int j = blockIdx.x, hl = blockIdx.y;
  const int t = threadIdx.x, lane = t & 63, wave = t >> 6;
  const int l16 = lane & 15, q4 = lane >> 4;
  const int fm = flag[0];

  // gather column-slice v2d[hl][p][j][0..63] -> T[d][p ^ d8blk]
  // (swizzle key (d>>3)<<3 == d8 for rows d8..d8+7; multiple of 8 keeps
  //  8-wide p-blocks contiguous for ds_read_b128; write banks 2-way-free)
  const unsigned short* vb = v2d + ((size_t)hl * 128) * 8192 + (size_t)j * 64;
#pragma unroll
  for (int it = 0; it < 4; ++it) {
    int c = it * 256 + t;               // 16B chunk id, 0..1023
    int p = c >> 3, d8 = (c & 7) * 8;   // p row in v2d, d-offset
    uint4 v = *(const uint4*)(vb + (size_t)p * 8192 + d8);
    unsigned short u[8];
    *(uint4*)u = v;
    int pc = p ^ d8;                    // X = (d8>>3)<<3 = d8
#pragma unroll
    for (int e = 0; e < 8; ++e) T[(d8 + e) * 136 + pc] = u[e];
  }
  __syncthreads();

  f4v acc[2][4];
#pragma unroll
  for (int a = 0; a < 2; ++a)
#pragma unroll
    for (int c = 0; c < 4; ++c) acc[a][c] = (f4v)0.f;

#pragma unroll
  for (int kc = 0; kc < 4; ++kc) {
    const int P0 = kc * 32 + q4 * 8;
    s8v a[2], bfr[4];
#pragma unroll
    for (int it = 0; it < 2; ++it)
      a[it] = *(const s8v*)(attn +
                            (((size_t)hl * 128 + (wave * 32 + it * 16 + l16)) * 128 + j) * 128 +
                            kc * 32 + q4 * 8);
#pragma unroll
    for (int dt = 0; dt < 4; ++dt) {
      int d = dt * 16 + l16;
      bfr[dt] = *(const s8v*)&T[d * 136 + (P0 ^ ((d >> 3) << 3))];
    }
#pragma unroll
    for (int it = 0; it < 2; ++it)
#pragma unroll
      for (int dt = 0; dt < 4; ++dt) acc[it][dt] = MFMA(a[it], bfr[dt], acc[it][dt]);
  }
#pragma unroll
  for (int it = 0; it < 2; ++it)
#pragma unroll
    for (int dt = 0; dt < 4; ++dt)
#pragma unroll
      for (int r = 0; r < 4; ++r) {
        int i = wave * 32 + it * 16 + q4 * 4 + r;
        int d = dt * 16 + l16;
        float o = acc[it][dt][r] + bf2f(out1[(((size_t)hl * 128 + i) * 128 + j) * 64 + d]);
        size_t oi = ((size_t)b * 16384 + i * 128 + j) * 512 + (h0 + hl) * 64 + d;
        if (fm) ((float*)out)[oi] = o;
        else    ((unsigned short*)out)[oi] = f2bf(o);
      }
}

// ---------------------------------------------------------------------------
extern "C" void kernel_launch(void* const* d_in, const int* in_sizes, int n_in,
                              void* d_out, int out_size, void* d_ws, size_t ws_size,
                              hipStream_t stream) {
  (void)in_sizes; (void)n_in; (void)out_size;
  const void* x = d_in[0];
  const void* w = d_in[1];

  const size_t xslice = (size_t)16384 * 512;
  const size_t wTsz = (size_t)2560 * 512;
  const size_t fixed = xslice * 4 + wTsz * 4 + 2560 * 4 + 64;

  int Hc = 2;
  if (30 * ((size_t)8 * 1048576) + fixed <= ws_size) Hc = 8;
  else if (30 * ((size_t)4 * 1048576) + fixed <= ws_size) Hc = 4;
  const int hcShift = (Hc == 8) ? 9 : ((Hc == 4) ? 8 : 7);
  const size_t TE = (size_t)Hc * 1048576;

  char* p = (char*)d_ws;
  unsigned short* qhi = (unsigned short*)p;  p += TE * 2;
  unsigned short* qlo = (unsigned short*)p;  p += TE * 2;
  unsigned short* k1hi = (unsigned short*)p; p += TE * 2;
  unsigned short* k1lo = (unsigned short*)p; p += TE * 2;
  unsigned short* k2hi = (unsigned short*)p; p += TE * 2;
  unsigned short* k2lo = (unsigned short*)p; p += TE * 2;
  unsigned short* v1T = (unsigned short*)p;  p += TE * 2;
  unsigned short* v2d = (unsigned short*)p;  p += TE * 2;   // old v2T slot
  float* S = (float*)p;                      p += TE * 8;
  unsigned short* attn = (unsigned short*)p; p += TE * 4;
  unsigned short* out1 = (unsigned short*)p; p += TE * 2;
  unsigned short* xhi = (unsigned short*)p;  p += xslice * 2;
  unsigned short* xlo = (unsigned short*)p;  p += xslice * 2;
  unsigned short* wThi = (unsigned short*)p; p += wTsz * 2;
  unsigned short* wTlo = (unsigned short*)p; p += wTsz * 2;
  float* colsum = (float*)p;                 p += 2560 * 4;
  double* dstats = (double*)p;               p += 16;
  int* flag = (int*)p;                       p += 8;
  float* fstats = (float*)p;                 p += 8;

  hipMemsetAsync(dstats, 0, 24, stream);  // dstats[2] + flag
  k_probe<<<1, 256, 0, stream>>>((const unsigned short*)x, flag);
  k_red<<<512, 256, 0, stream>>>(x, flag, dstats);
  k_stats<<<1, 1, 0, stream>>>(dstats, fstats);
  k_colsum<<<10, 256, 0, stream>>>(w, flag, colsum);
  k_wt<<<dim3(40, 8), 256, 0, stream>>>(w, flag, wThi, wTlo);

  for (int b = 0; b < 4; ++b) {
    k_convx<<<4096, 256, 0, stream>>>(x, flag, xhi, xlo, b);
    for (int h0 = 0; h0 < 8; h0 += Hc) {
      const int nwgy = (5 * Hc * 64) / 128;
      k_gemm<<<dim3(128 * nwgy), 256, 0, stream>>>(
          xhi, xlo, wThi, wTlo, colsum, fstats, flag,
          qhi, qlo, k1hi, k1lo, k2hi, k2lo, v1T, v2d, h0, hcShift, nwgy);
      k_s1<<<dim3(128, Hc), 256, 0, stream>>>(qhi, qlo, k1hi, k1lo, S);
      k_s2<<<dim3(128, Hc), 256, 0, stream>>>(qhi, qlo, k2hi, k2lo, S, attn);
      k_av1<<<dim3(128, Hc), 256, 0, stream>>>(attn, v1T, out1);
      k_av2<<<dim3(128, Hc), 256, 0, stream>>>(attn, v2d, out1, flag, d_out, b, h0);
    }
  }
}

// Round 10
// 1473.169 us; speedup vs baseline: 1.0467x; 1.0467x over previous
//
#include <hip/hip_runtime.h>
#include <stdint.h>

// ---------------------------------------------------------------------------
// FloydBlock2: global-norm -> QKV GEMM -> pivotal attention (row+col streams)
// B=4, N=128, C=512, H=8, D=64, SCALE=6.25
// Dtype-adaptive (probe): fp32 or bf16 I/O. GEMM uses hi/lo bf16 splits.
// R5: counted-vmcnt BK=32 dbuf pipeline. R7: v2 dense + k_v2t.
// R10: 1-D grid + verified XCD swizzle -> 187us/launch, total 1500us (BEST).
// R11: av2-into-s2 fusion NEUTRAL -> reverted. R12: k_v2t deletion -42us
//      launches but +100us serialized gather in k_av2 -> reverted.
// R13: R10 + LDS-staged GEMM epilogue. Diagnosis: FETCH(186MB) ~= WRITE
//      (186MB) >> input footprint (75MB) -> ~110MB is L2 write-allocate
//      fetch from 2B-scattered epilogue stores. Fix: stage each output
//      128x64 half-tile in the (dead) staging LDS with XOR-swizzled
//      layout, stream out as dense uint4 full-line stores.
// ---------------------------------------------------------------------------

typedef __attribute__((ext_vector_type(8))) short s8v;   // 8 x bf16 (4 VGPRs)
typedef __attribute__((ext_vector_type(4))) float f4v;   // MFMA accumulator

#define MFMA(a, b, c) __builtin_amdgcn_mfma_f32_16x16x32_bf16((a), (b), (c), 0, 0, 0)

__device__ __forceinline__ float bf2f(unsigned short u) {
  union { unsigned int i; float f; } v; v.i = ((unsigned int)u) << 16; return v.f;
}
__device__ __forceinline__ unsigned short f2bf(float f) {
  union { float f; unsigned int i; } v; v.f = f;
  unsigned int i = v.i;
  return (unsigned short)((i + 0x7fffu + ((i >> 16) & 1u)) >> 16);  // RNE
}

__device__ __forceinline__ void async_copy16(const void* g, void* l) {
  __builtin_amdgcn_global_load_lds(
      (const __attribute__((address_space(1))) unsigned int*)(uintptr_t)g,
      (__attribute__((address_space(3))) unsigned int*)(uintptr_t)l,
      16, 0, 0);
}

// ---------------------------------------------------------------------------
// 0) dtype probe
// ---------------------------------------------------------------------------
__global__ __launch_bounds__(256) void k_probe(const unsigned short* __restrict__ x,
                                               int* __restrict__ flag) {
  uint4 v = ((const uint4*)x)[threadIdx.x];
  unsigned int uu[4] = {v.x, v.y, v.z, v.w};
  int bad = 0;
#pragma unroll
  for (int u = 0; u < 4; ++u) {
    float a = bf2f((unsigned short)(uu[u] & 0xffffu));
    float b = bf2f((unsigned short)(uu[u] >> 16));
    if (!(fabsf(a) <= 1e4f)) bad = 1;
    if (!(fabsf(b) <= 1e4f)) bad = 1;
  }
  if (bad) atomicOr(flag, 1);
}

// ---------------------------------------------------------------------------
// 1) Global sum / sumsq over raw x
// ---------------------------------------------------------------------------
__global__ __launch_bounds__(256) void k_red(const void* __restrict__ xraw,
                                             const int* __restrict__ flag,
                                             double* __restrict__ dstats) {
  __shared__ float red[8];
  const int fm = flag[0];
  int t = threadIdx.x;
  size_t gid = (size_t)blockIdx.x * 256 + t;
  float s = 0.f, ss = 0.f;
  if (fm) {
    const float4* pf = (const float4*)xraw;
#pragma unroll 4
    for (int it = 0; it < 32; ++it) {
      size_t idx = gid + (size_t)it * 131072;
      float4 u1 = pf[2 * idx], u2 = pf[2 * idx + 1];
      float vals[8] = {u1.x, u1.y, u1.z, u1.w, u2.x, u2.y, u2.z, u2.w};
#pragma unroll
      for (int u = 0; u < 8; ++u) { s += vals[u]; ss += vals[u] * vals[u]; }
    }
  } else {
    const uint4* p = (const uint4*)xraw;
#pragma unroll 4
    for (int it = 0; it < 32; ++it) {
      uint4 v = p[gid + (size_t)it * 131072];
      unsigned int uu[4] = {v.x, v.y, v.z, v.w};
#pragma unroll
      for (int u = 0; u < 4; ++u) {
        float a = bf2f((unsigned short)(uu[u] & 0xffffu));
        float b = bf2f((unsigned short)(uu[u] >> 16));
        s += a + b;
        ss += a * a + b * b;
      }
    }
  }
#pragma unroll
  for (int d = 32; d >= 1; d >>= 1) {
    s += __shfl_down(s, d);
    ss += __shfl_down(ss, d);
  }
  int lane = t & 63, wave = t >> 6;
  if (lane == 0) { red[wave] = s; red[4 + wave] = ss; }
  __syncthreads();
  if (t == 0) {
    atomicAdd(&dstats[0], (double)(red[0] + red[1] + red[2] + red[3]));
    atomicAdd(&dstats[1], (double)(red[4] + red[5] + red[6] + red[7]));
  }
}

__global__ void k_stats(const double* __restrict__ dstats, float* __restrict__ fstats) {
  double M = 33554432.0;
  double mean = dstats[0] / M;
  double var = (dstats[1] - dstats[0] * dstats[0] / M) / (M - 1.0);  // ddof=1
  double istd = 1.0 / sqrt(var);
  fstats[0] = (float)istd;
  fstats[1] = (float)(-mean * istd);
}

__global__ __launch_bounds__(256) void k_colsum(const void* __restrict__ wraw,
                                                const int* __restrict__ flag,
                                                float* __restrict__ colsum) {
  const int fm = flag[0];
  int c = blockIdx.x * 256 + threadIdx.x;
  if (c >= 2560) return;
  float s = 0.f;
  if (fm) {
    const float* w = (const float*)wraw;
    for (int r = 0; r < 512; ++r) s += w[(size_t)r * 2560 + c];
  } else {
    const unsigned short* w = (const unsigned short*)wraw;
    for (int r = 0; r < 512; ++r) s += bf2f(w[(size_t)r * 2560 + c]);
  }
  colsum[c] = s;
}

// wT hi/lo [n][k] = split(w[k][n])  (2560 x 512)
__global__ __launch_bounds__(256) void k_wt(const void* __restrict__ wraw,
                                            const int* __restrict__ flag,
                                            unsigned short* __restrict__ wThi,
                                            unsigned short* __restrict__ wTlo) {
  __shared__ float tile[64][65];
  const int fm = flag[0];
  int n0 = blockIdx.x * 64, r0 = blockIdx.y * 64;
#pragma unroll
  for (int rep = 0; rep < 16; ++rep) {
    int idx = rep * 256 + threadIdx.x;
    int r = idx >> 6, n = idx & 63;
    float v;
    if (fm) v = ((const float*)wraw)[(size_t)(r0 + r) * 2560 + n0 + n];
    else    v = bf2f(((const unsigned short*)wraw)[(size_t)(r0 + r) * 2560 + n0 + n]);
    tile[r][n] = v;
  }
  __syncthreads();
#pragma unroll
  for (int rep = 0; rep < 16; ++rep) {
    int idx = rep * 256 + threadIdx.x;
    int n = idx >> 6, r = idx & 63;
    float v = tile[r][n];
    unsigned short hi = f2bf(v);
    size_t o = (size_t)(n0 + n) * 512 + r0 + r;
    wThi[o] = hi;
    wTlo[o] = f2bf(v - bf2f(hi));
  }
}

// per-b slice conversion: x[b] -> xhi/xlo bf16 [16384][512]
__global__ __launch_bounds__(256) void k_convx(const void* __restrict__ xraw,
                                               const int* __restrict__ flag,
                                               unsigned short* __restrict__ xhi,
                                               unsigned short* __restrict__ xlo,
                                               int b) {
  const int fm = flag[0];
  size_t e0 = ((size_t)blockIdx.x * 256 + threadIdx.x) * 8;
  size_t g0 = (size_t)b * 8388608 + e0;
  float vals[8];
  if (fm) {
    const float4* pf = (const float4*)xraw;
    float4 u1 = pf[g0 / 4], u2 = pf[g0 / 4 + 1];
    vals[0] = u1.x; vals[1] = u1.y; vals[2] = u1.z; vals[3] = u1.w;
    vals[4] = u2.x; vals[5] = u2.y; vals[6] = u2.z; vals[7] = u2.w;
  } else {
    uint4 v = ((const uint4*)xraw)[g0 / 8];
    unsigned int uu[4] = {v.x, v.y, v.z, v.w};
#pragma unroll
    for (int u = 0; u < 4; ++u) {
      vals[2 * u] = bf2f((unsigned short)(uu[u] & 0xffffu));
      vals[2 * u + 1] = bf2f((unsigned short)(uu[u] >> 16));
    }
  }
  unsigned short h[8], l[8];
#pragma unroll
  for (int u = 0; u < 8; ++u) {
    h[u] = f2bf(vals[u]);
    l[u] = f2bf(vals[u] - bf2f(h[u]));
  }
  *(uint4*)(xhi + e0) = *(const uint4*)h;
  *(uint4*)(xlo + e0) = *(const uint4*)l;
}

// ---------------------------------------------------------------------------
// 2) QKV GEMM, 128x128 tiles, BK=32 double-buffered, hi/lo 3-term MFMA.
//    Counted-vmcnt pipeline + verified XCD swizzle (R10).
//    R13: LDS-staged epilogue -> dense uint4 stores (no write-allocate RMW).
// ---------------------------------------------------------------------------
__global__ __launch_bounds__(256) void k_gemm(
    const unsigned short* __restrict__ xhi, const unsigned short* __restrict__ xlo,
    const unsigned short* __restrict__ wThi, const unsigned short* __restrict__ wTlo,
    const float* __restrict__ colsum, const float* __restrict__ fstats,
    const int* __restrict__ flag,
    unsigned short* __restrict__ qhi, unsigned short* __restrict__ qlo,
    unsigned short* __restrict__ k1hi, unsigned short* __restrict__ k1lo,
    unsigned short* __restrict__ k2hi, unsigned short* __restrict__ k2lo,
    unsigned short* __restrict__ v1T, unsigned short* __restrict__ v2d,
    int h0, int hcShift, int nwgy) {
  __shared__ __align__(16) unsigned short SMEM[32768];   // 64KB flat
  unsigned short* Ash = SMEM;            // [2][4096]
  unsigned short* Asl = SMEM + 8192;
  unsigned short* Bsh = SMEM + 16384;
  unsigned short* Bsl = SMEM + 24576;
  const int fm = flag[0];
  const int t = threadIdx.x;

  // verified XCD mapping on 1-D grid (nwg = 128*nwgy, nwg%8==0).
  const int vid = blockIdx.x;
  const int xcd = vid & 7, seq = vid >> 3;
  const int m0 = (xcd * 16 + seq / nwgy) * 128;
  const int n0 = (seq % nwgy) * 128;

  const int hcMask = (1 << hcShift) - 1;

  const int lane = t & 63, wave = t >> 6;
  const int wm = (wave & 1) * 64, wn = (wave >> 1) * 64;
  const int l16 = lane & 15, q4 = lane >> 4;

  const int srow0 = t >> 2;
  const int srow1 = 64 + srow0;
  const int sch = (((t & 3) ^ ((t >> 3) & 3)) << 3);     // element offset in row
  const int swoff = ((q4 ^ ((l16 >> 1) & 3)) << 3);

  const float af = fstats[0], bfc = fstats[1];
  const unsigned short* xh = xhi + (size_t)m0 * 512;
  const unsigned short* xl = xlo + (size_t)m0 * 512;

  int wcol0, wcol1;
  {
    int n = n0 + srow0, g = n >> hcShift, rem = n & hcMask;
    wcol0 = (g << 9) + ((h0 + (rem >> 6)) << 6) + (rem & 63);
    n = n0 + srow1; g = n >> hcShift; rem = n & hcMask;
    wcol1 = (g << 9) + ((h0 + (rem >> 6)) << 6) + (rem & 63);
  }

  f4v acc[4][4];
#pragma unroll
  for (int a = 0; a < 4; ++a)
#pragma unroll
    for (int c = 0; c < 4; ++c) acc[a][c] = (f4v)0.f;

  auto STAGE = [&](int bsel, int k0) {
    async_copy16(xh + (size_t)srow0 * 512 + k0 + sch, (char*)(Ash + bsel * 4096) + t * 16);
    async_copy16(xh + (size_t)srow1 * 512 + k0 + sch, (char*)(Ash + bsel * 4096) + (256 + t) * 16);
    async_copy16(wThi + (size_t)wcol0 * 512 + k0 + sch, (char*)(Bsh + bsel * 4096) + t * 16);
    async_copy16(wThi + (size_t)wcol1 * 512 + k0 + sch, (char*)(Bsh + bsel * 4096) + (256 + t) * 16);
    if (fm) {
      async_copy16(xl + (size_t)srow0 * 512 + k0 + sch, (char*)(Asl + bsel * 4096) + t * 16);
      async_copy16(xl + (size_t)srow1 * 512 + k0 + sch, (char*)(Asl + bsel * 4096) + (256 + t) * 16);
      async_copy16(wTlo + (size_t)wcol0 * 512 + k0 + sch, (char*)(Bsl + bsel * 4096) + t * 16);
      async_copy16(wTlo + (size_t)wcol1 * 512 + k0 + sch, (char*)(Bsl + bsel * 4096) + (256 + t) * 16);
    }
  };

  STAGE(0, 0);

#pragma unroll 2
  for (int ks = 0; ks < 16; ++ks) {
    const int kb = ks & 1;
    if (ks < 15) {
      STAGE(kb ^ 1, (ks + 1) << 5);   // prefetch next tile (other buf)
      if (fm) asm volatile("s_waitcnt vmcnt(8)" ::: "memory");
      else    asm volatile("s_waitcnt vmcnt(4)" ::: "memory");
    } else {
      asm volatile("s_waitcnt vmcnt(0)" ::: "memory");  // epilogue drain
    }
    __builtin_amdgcn_s_barrier();     // all waves' buf[kb] loads landed

    s8v ah[4], bh[4];
#pragma unroll
    for (int jt = 0; jt < 4; ++jt)
      ah[jt] = *(const s8v*)&Ash[kb * 4096 + (wm + jt * 16 + l16) * 32 + swoff];
#pragma unroll
    for (int nt = 0; nt < 4; ++nt)
      bh[nt] = *(const s8v*)&Bsh[kb * 4096 + (wn + nt * 16 + l16) * 32 + swoff];
    if (fm) {
      s8v al[4], bl[4];
#pragma unroll
      for (int jt = 0; jt < 4; ++jt)
        al[jt] = *(const s8v*)&Asl[kb * 4096 + (wm + jt * 16 + l16) * 32 + swoff];
#pragma unroll
      for (int nt = 0; nt < 4; ++nt)
        bl[nt] = *(const s8v*)&Bsl[kb * 4096 + (wn + nt * 16 + l16) * 32 + swoff];
#pragma unroll
      for (int jt = 0; jt < 4; ++jt)
#pragma unroll
        for (int nt = 0; nt < 4; ++nt) {
          acc[jt][nt] = MFMA(ah[jt], bh[nt], acc[jt][nt]);
          acc[jt][nt] = MFMA(ah[jt], bl[nt], acc[jt][nt]);
          acc[jt][nt] = MFMA(al[jt], bh[nt], acc[jt][nt]);
        }
    } else {
#pragma unroll
      for (int jt = 0; jt < 4; ++jt)
#pragma unroll
        for (int nt = 0; nt < 4; ++nt) acc[jt][nt] = MFMA(ah[jt], bh[nt], acc[jt][nt]);
    }
    asm volatile("" ::: "memory");    // pin ds_reads above the barrier
    __builtin_amdgcn_s_barrier();     // buf[kb] free for ks+1's STAGE
  }

  // ---- R13 staged epilogue. SMEM (64KB) is dead after the final barrier.
  // Block output = 128 rows x 128 cols = one head-group g, 2 hl halves.
  // Each wave owns one hl half (wn). Tiles: 2 x 8192 el (32KB).
  const int g = n0 >> hcShift;                 // block-uniform
  const int hlbase = (n0 & hcMask) >> 6;
  const int iBlk = m0 >> 7;
  const int hl_l = wave >> 1;                  // this wave's hl half

  float cs[4];
#pragma unroll
  for (int nt = 0; nt < 4; ++nt) {
    int gcol = n0 + wn + nt * 16 + l16;
    int rem = gcol & hcMask;
    int wcol = (g << 9) + ((h0 + (rem >> 6)) << 6) + (rem & 63);
    cs[nt] = colsum[wcol] * bfc;
  }

  if (g <= 2) {
    unsigned short* dh = (g == 0) ? qhi : (g == 1) ? k1hi : k2hi;
    unsigned short* dl = (g == 0) ? qlo : (g == 1) ? k1lo : k2lo;
#pragma unroll
    for (int part = 0; part < 2; ++part) {
      // stage: T[j*64 + (d ^ ((j>>2)&3)<<4)]  (conflict-free, chunk-aligned)
#pragma unroll
      for (int jt = 0; jt < 4; ++jt)
#pragma unroll
        for (int nt = 0; nt < 4; ++nt) {
          int d = nt * 16 + l16;
#pragma unroll
          for (int r = 0; r < 4; ++r) {
            int j = wm + jt * 16 + q4 * 4 + r;
            float val = acc[jt][nt][r] * af + cs[nt];
            unsigned short hi = f2bf(val);
            unsigned short vv = part ? f2bf(val - bf2f(hi)) : hi;
            SMEM[hl_l * 8192 + j * 64 + (d ^ (((j >> 2) & 3) << 4))] = vv;
          }
        }
      __syncthreads();
      unsigned short* dst = part ? dl : dh;
#pragma unroll
      for (int it = 0; it < 8; ++it) {
        int c = it * 256 + t;
        int hh = c >> 10, o = (c & 1023) * 8;
        int j = o >> 6, d0 = o & 63;
        uint4 v = *(const uint4*)&SMEM[hh * 8192 + j * 64 + (d0 ^ (((j >> 2) & 3) << 4))];
        int hl = hlbase + hh;
        if (g == 2) {
          size_t a = ((size_t)hl * 16384 + iBlk) * 64 + (size_t)j * 8192 + d0;
          *(uint4*)&dst[a] = v;
        } else {
          size_t a = (((size_t)hl * 128 + iBlk) * 128) * 64 + o;
          *(uint4*)&dst[a] = v;
        }
      }
      __syncthreads();
    }
  } else if (g == 4) {
    // v2 dense [hl][p=i][j][d]: q layout, hi only
#pragma unroll
    for (int jt = 0; jt < 4; ++jt)
#pragma unroll
      for (int nt = 0; nt < 4; ++nt) {
        int d = nt * 16 + l16;
#pragma unroll
        for (int r = 0; r < 4; ++r) {
          int j = wm + jt * 16 + q4 * 4 + r;
          float val = acc[jt][nt][r] * af + cs[nt];
          SMEM[hl_l * 8192 + j * 64 + (d ^ (((j >> 2) & 3) << 4))] = f2bf(val);
        }
      }
    __syncthreads();
#pragma unroll
    for (int it = 0; it < 8; ++it) {
      int c = it * 256 + t;
      int hh = c >> 10, o = (c & 1023) * 8;
      int j = o >> 6, d0 = o & 63;
      uint4 v = *(const uint4*)&SMEM[hh * 8192 + j * 64 + (d0 ^ (((j >> 2) & 3) << 4))];
      int hl = hlbase + hh;
      size_t a = (((size_t)hl * 128 + iBlk) * 128) * 64 + o;
      *(uint4*)&v2d[a] = v;
    }
  } else {
    // g==3: v1T [hl][i][d][j]: d-major tile T[d*128 + (j ^ (d&3)<<4)]
#pragma unroll
    for (int jt = 0; jt < 4; ++jt)
#pragma unroll
      for (int nt = 0; nt < 4; ++nt) {
        int d = nt * 16 + l16;
        int key = (d & 3) << 4;
#pragma unroll
        for (int r = 0; r < 4; ++r) {
          int j = wm + jt * 16 + q4 * 4 + r;
          float val = acc[jt][nt][r] * af + cs[nt];
          SMEM[hl_l * 8192 + d * 128 + (j ^ key)] = f2bf(val);
        }
      }
    __syncthreads();
#pragma unroll
    for (int it = 0; it < 8; ++it) {
      int c = it * 256 + t;
      int hh = c >> 10, o = (c & 1023) * 8;   // o = d*128 + j0
      int d = o >> 7, j0 = o & 127;
      uint4 v = *(const uint4*)&SMEM[hh * 8192 + d * 128 + (j0 ^ ((d & 3) << 4))];
      int hl = hlbase + hh;
      size_t a = (((size_t)hl * 128 + iBlk) * 64) * 128 + o;
      *(uint4*)&v1T[a] = v;
    }
  }
}

// ---------------------------------------------------------------------------
// 2b) v2 transpose: [hl][p][j][d] -> [hl][j][d][p]. Per (hl,j): 16KB tile via
//     swizzled LDS; coalesced 128B reads / 256B writes.
// ---------------------------------------------------------------------------
__global__ __launch_bounds__(256) void k_v2t(const unsigned short* __restrict__ v2d,
                                             unsigned short* __restrict__ v2T) {
  __shared__ unsigned short T[128][72];   // pad 72 (16B-aligned rows)
  const int j = blockIdx.x, hl = blockIdx.y;
  const int t = threadIdx.x;
  const unsigned short* ib = v2d + ((size_t)hl * 128) * 8192 + (size_t)j * 64;
#pragma unroll
  for (int it = 0; it < 4; ++it) {
    int c = it * 256 + t;                 // 0..1023 chunks of 8 bf16
    int p = c >> 3, d8 = (c & 7) * 8;
    uint4 v = *(const uint4*)(ib + (size_t)p * 8192 + d8);
    *(uint4*)&T[p][d8 ^ (((p >> 3) & 7) << 3)] = v;   // col-swizzle by p-group
  }
  __syncthreads();
  unsigned short* ob = v2T + (((size_t)hl * 128 + j) * 64) * 128;
#pragma unroll
  for (int it = 0; it < 4; ++it) {
    int c = it * 256 + t;
    int d = c >> 4, p8 = (c & 15) * 8;
    int dz = d ^ (((p8 >> 3) & 7) << 3);  // same swizzle key (p>>3 const over e)
    unsigned short u[8];
#pragma unroll
    for (int e = 0; e < 8; ++e) u[e] = T[p8 + e][dz];
    *(uint4*)&ob[(size_t)d * 128 + p8] = *(const uint4*)u;
  }
}

// ---------------------------------------------------------------------------
// 3) S1[j,k] = sum_d q[i,j,d]*k1[i,k,d] per (hl, i)
// ---------------------------------------------------------------------------
__global__ __launch_bounds__(256) void k_s1(
    const unsigned short* __restrict__ qhi, const unsigned short* __restrict__ qlo,
    const unsigned short* __restrict__ k1hi, const unsigned short* __restrict__ k1lo,
    float* __restrict__ S) {
  const int i = blockIdx.x, hl = blockIdx.y;
  const int t = threadIdx.x, lane = t & 63, wave = t >> 6;
  const int l16 = lane & 15, q4 = lane >> 4;
  const size_t base = ((size_t)hl * 128 + i) * 128 * 64;

  f4v acc[2][8];
#pragma unroll
  for (int a = 0; a < 2; ++a)
#pragma unroll
    for (int c = 0; c < 8; ++c) acc[a][c] = (f4v)0.f;

#pragma unroll
  for (int kc = 0; kc < 2; ++kc) {
    s8v ah[2], al[2];
#pragma unroll
    for (int jt = 0; jt < 2; ++jt) {
      size_t off = base + (size_t)(wave * 32 + jt * 16 + l16) * 64 + kc * 32 + q4 * 8;
      ah[jt] = *(const s8v*)(qhi + off);
      al[jt] = *(const s8v*)(qlo + off);
    }
#pragma unroll
    for (int kt = 0; kt < 8; ++kt) {
      size_t off = base + (size_t)(kt * 16 + l16) * 64 + kc * 32 + q4 * 8;
      s8v bh = *(const s8v*)(k1hi + off);
      s8v bl = *(const s8v*)(k1lo + off);
#pragma unroll
      for (int jt = 0; jt < 2; ++jt) {
        acc[jt][kt] = MFMA(ah[jt], bh, acc[jt][kt]);
        acc[jt][kt] = MFMA(ah[jt], bl, acc[jt][kt]);
        acc[jt][kt] = MFMA(al[jt], bh, acc[jt][kt]);
      }
    }
  }
  float* Sb = S + ((size_t)hl * 128 + i) * 128 * 128;
#pragma unroll
  for (int jt = 0; jt < 2; ++jt)
#pragma unroll
    for (int kt = 0; kt < 8; ++kt)
#pragma unroll
      for (int r = 0; r < 4; ++r) {
        int j = wave * 32 + jt * 16 + q4 * 4 + r;
        Sb[(size_t)j * 128 + kt * 16 + l16] = acc[jt][kt][r];
      }
}

// ---------------------------------------------------------------------------
// 4) S2[i,k] per (hl, j); add S1, scale, softmax over k, write attn bf16
// ---------------------------------------------------------------------------
__global__ __launch_bounds__(256) void k_s2(
    const unsigned short* __restrict__ qhi, const unsigned short* __restrict__ qlo,
    const unsigned short* __restrict__ k2hi, const unsigned short* __restrict__ k2lo,
    const float* __restrict__ S, unsigned short* __restrict__ attn) {
  const int j = blockIdx.x, hl = blockIdx.y;
  const int t = threadIdx.x, lane = t & 63, wave = t >> 6;
  const int l16 = lane & 15, q4 = lane >> 4;
  const size_t bbase = ((size_t)hl * 128 + j) * 128 * 64;

  f4v acc[2][8];
#pragma unroll
  for (int a = 0; a < 2; ++a)
#pragma unroll
    for (int c = 0; c < 8; ++c) acc[a][c] = (f4v)0.f;

#pragma unroll
  for (int kc = 0; kc < 2; ++kc) {
    s8v ah[2], al[2];
#pragma unroll
    for (int it = 0; it < 2; ++it) {
      size_t off = (((size_t)hl * 128 + (wave * 32 + it * 16 + l16)) * 128 + j) * 64 +
                   kc * 32 + q4 * 8;
      ah[it] = *(const s8v*)(qhi + off);
      al[it] = *(const s8v*)(qlo + off);
    }
#pragma unroll
    for (int kt = 0; kt < 8; ++kt) {
      size_t off = bbase + (size_t)(kt * 16 + l16) * 64 + kc * 32 + q4 * 8;
      s8v bh = *(const s8v*)(k2hi + off);
      s8v bl = *(const s8v*)(k2lo + off);
#pragma unroll
      for (int it = 0; it < 2; ++it) {
        acc[it][kt] = MFMA(ah[it], bh, acc[it][kt]);
        acc[it][kt] = MFMA(ah[it], bl, acc[it][kt]);
        acc[it][kt] = MFMA(al[it], bh, acc[it][kt]);
      }
    }
  }

#pragma unroll
  for (int it = 0; it < 2; ++it) {
#pragma unroll
    for (int r = 0; r < 4; ++r) {
      int i = wave * 32 + it * 16 + q4 * 4 + r;
      const float* Srow = S + (((size_t)hl * 128 + i) * 128 + j) * 128;
      float tv[8];
      float m = -3.4e38f;
#pragma unroll
      for (int kt = 0; kt < 8; ++kt) {
        tv[kt] = 6.25f * (Srow[kt * 16 + l16] + acc[it][kt][r]);
        m = fmaxf(m, tv[kt]);
      }
#pragma unroll
      for (int d = 1; d <= 8; d <<= 1) m = fmaxf(m, __shfl_xor(m, d));
      float sum = 0.f;
#pragma unroll
      for (int kt = 0; kt < 8; ++kt) {
        tv[kt] = __expf(tv[kt] - m);
        sum += tv[kt];
      }
#pragma unroll
      for (int d = 1; d <= 8; d <<= 1) sum += __shfl_xor(sum, d);
      float rs = 1.f / sum;
      unsigned short* arow = attn + (((size_t)hl * 128 + i) * 128 + j) * 128;
#pragma unroll
      for (int kt = 0; kt < 8; ++kt) arow[kt * 16 + l16] = f2bf(tv[kt] * rs);
    }
  }
}

// ---------------------------------------------------------------------------
// 5) O1[j,d] = sum_k attn[i,j,k]*v1[i,k,d] per (hl, i); out1 bf16
// ---------------------------------------------------------------------------
__global__ __launch_bounds__(256) void k_av1(
    const unsigned short* __restrict__ attn, const unsigned short* __restrict__ v1T,
    unsigned short* __restrict__ out1) {
  const int i = blockIdx.x, hl = blockIdx.y;
  const int t = threadIdx.x, lane = t & 63, wave = t >> 6;
  const int l16 = lane & 15, q4 = lane >> 4;
  const size_t abase = ((size_t)hl * 128 + i) * 128 * 128;
  const size_t vbase = ((size_t)hl * 128 + i) * 64 * 128;

  f4v acc[2][4];
#pragma unroll
  for (int a = 0; a < 2; ++a)
#pragma unroll
    for (int c = 0; c < 4; ++c) acc[a][c] = (f4v)0.f;

#pragma unroll
  for (int kc = 0; kc < 4; ++kc) {
    s8v a[2], bfr[4];
#pragma unroll
    for (int jt = 0; jt < 2; ++jt)
      a[jt] = *(const s8v*)(attn + abase + (size_t)(wave * 32 + jt * 16 + l16) * 128 +
                            kc * 32 + q4 * 8);
#pragma unroll
    for (int dt = 0; dt < 4; ++dt)
      bfr[dt] = *(const s8v*)(v1T + vbase + (size_t)(dt * 16 + l16) * 128 + kc * 32 + q4 * 8);
#pragma unroll
    for (int jt = 0; jt < 2; ++jt)
#pragma unroll
      for (int dt = 0; dt < 4; ++dt) acc[jt][dt] = MFMA(a[jt], bfr[dt], acc[jt][dt]);
  }
  unsigned short* ob = out1 + ((size_t)hl * 128 + i) * 128 * 64;
#pragma unroll
  for (int jt = 0; jt < 2; ++jt)
#pragma unroll
    for (int dt = 0; dt < 4; ++dt)
#pragma unroll
      for (int r = 0; r < 4; ++r) {
        int j = wave * 32 + jt * 16 + q4 * 4 + r;
        ob[(size_t)j * 64 + dt * 16 + l16] = f2bf(acc[jt][dt][r]);
      }
}

// ---------------------------------------------------------------------------
// 6) O2[i,d] per (hl, j); add out1, dtype-branched final store
// ---------------------------------------------------------------------------
__global__ __launch_bounds__(256) void k_av2(
    const unsigned short* __restrict__ attn, const unsigned short* __restrict__ v2T,
    const unsigned short* __restrict__ out1, const int* __restrict__ flag,
    void* __restrict__ out, int b, int h0) {
  const int j = blockIdx.x, hl = blockIdx.y;
  const int t = threadIdx.x, lane = t & 63, wave = t >> 6;
  const int l16 = lane & 15, q4 = lane >> 4;
  const int fm = flag[0];
  const size_t vbase = ((size_t)hl * 128 + j) * 64 * 128;

  f4v acc[2][4];
#pragma unroll
  for (int a = 0; a < 2; ++a)
#pragma unroll
    for (int c = 0; c < 4; ++c) acc[a][c] = (f4v)0.f;

#pragma unroll
  for (int kc = 0; kc < 4; ++kc) {
    s8v a[2], bfr[4];
#pragma unroll
    for (int it = 0; it < 2; ++it)
      a[it] = *(const s8v*)(attn +
                            (((size_t)hl * 128 + (wave * 32 + it * 16 + l16)) * 128 + j) * 128 +
                            kc * 32 + q4 * 8);
#pragma unroll
    for (int dt = 0; dt < 4; ++dt)
      bfr[dt] = *(const s8v*)(v2T + vbase + (size_t)(dt * 16 + l16) * 128 + kc * 32 + q4 * 8);
#pragma unroll
    for (int it = 0; it < 2; ++it)
#pragma unroll
      for (int dt = 0; dt < 4; ++dt) acc[it][dt] = MFMA(a[it], bfr[dt], acc[it][dt]);
  }
#pragma unroll
  for (int it = 0; it < 2; ++it)
#pragma unroll
    for (int dt = 0; dt < 4; ++dt)
#pragma unroll
      for (int r = 0; r < 4; ++r) {
        int i = wave * 32 + it * 16 + q4 * 4 + r;
        int d = dt * 16 + l16;
        float o = acc[it][dt][r] + bf2f(out1[(((size_t)hl * 128 + i) * 128 + j) * 64 + d]);
        size_t oi = ((size_t)b * 16384 + i * 128 + j) * 512 + (h0 + hl) * 64 + d;
        if (fm) ((float*)out)[oi] = o;
        else    ((unsigned short*)out)[oi] = f2bf(o);
      }
}

// ---------------------------------------------------------------------------
extern "C" void kernel_launch(void* const* d_in, const int* in_sizes, int n_in,
                              void* d_out, int out_size, void* d_ws, size_t ws_size,
                              hipStream_t stream) {
  (void)in_sizes; (void)n_in; (void)out_size;
  const void* x = d_in[0];
  const void* w = d_in[1];

  const size_t xslice = (size_t)16384 * 512;
  const size_t wTsz = (size_t)2560 * 512;
  const size_t fixed = xslice * 4 + wTsz * 4 + 2560 * 4 + 64;

  int Hc = 2;
  if (30 * ((size_t)8 * 1048576) + fixed <= ws_size) Hc = 8;
  else if (30 * ((size_t)4 * 1048576) + fixed <= ws_size) Hc = 4;
  const int hcShift = (Hc == 8) ? 9 : ((Hc == 4) ? 8 : 7);
  const size_t TE = (size_t)Hc * 1048576;

  char* p = (char*)d_ws;
  unsigned short* qhi = (unsigned short*)p;  p += TE * 2;
  unsigned short* qlo = (unsigned short*)p;  p += TE * 2;
  unsigned short* k1hi = (unsigned short*)p; p += TE * 2;
  unsigned short* k1lo = (unsigned short*)p; p += TE * 2;
  unsigned short* k2hi = (unsigned short*)p; p += TE * 2;
  unsigned short* k2lo = (unsigned short*)p; p += TE * 2;
  unsigned short* v1T = (unsigned short*)p;  p += TE * 2;
  unsigned short* v2T = (unsigned short*)p;  p += TE * 2;
  float* S = (float*)p;                      p += TE * 8;
  unsigned short* attn = (unsigned short*)p; p += TE * 4;
  unsigned short* out1 = (unsigned short*)p; p += TE * 2;
  unsigned short* xhi = (unsigned short*)p;  p += xslice * 2;
  unsigned short* xlo = (unsigned short*)p;  p += xslice * 2;
  unsigned short* wThi = (unsigned short*)p; p += wTsz * 2;
  unsigned short* wTlo = (unsigned short*)p; p += wTsz * 2;
  float* colsum = (float*)p;                 p += 2560 * 4;
  double* dstats = (double*)p;               p += 16;
  int* flag = (int*)p;                       p += 8;
  float* fstats = (float*)p;                 p += 8;

  // v2 dense staging aliases S (S is written only later, by k_s1)
  unsigned short* v2d = (unsigned short*)S;

  hipMemsetAsync(dstats, 0, 24, stream);  // dstats[2] + flag
  k_probe<<<1, 256, 0, stream>>>((const unsigned short*)x, flag);
  k_red<<<512, 256, 0, stream>>>(x, flag, dstats);
  k_stats<<<1, 1, 0, stream>>>(dstats, fstats);
  k_colsum<<<10, 256, 0, stream>>>(w, flag, colsum);
  k_wt<<<dim3(40, 8), 256, 0, stream>>>(w, flag, wThi, wTlo);

  for (int b = 0; b < 4; ++b) {
    k_convx<<<4096, 256, 0, stream>>>(x, flag, xhi, xlo, b);
    for (int h0 = 0; h0 < 8; h0 += Hc) {
      const int nwgy = (5 * Hc * 64) / 128;
      k_gemm<<<dim3(128 * nwgy), 256, 0, stream>>>(
          xhi, xlo, wThi, wTlo, colsum, fstats, flag,
          qhi, qlo, k1hi, k1lo, k2hi, k2lo, v1T, v2d, h0, hcShift, nwgy);
      k_v2t<<<dim3(128, Hc), 256, 0, stream>>>(v2d, v2T);
      k_s1<<<dim3(128, Hc), 256, 0, stream>>>(qhi, qlo, k1hi, k1lo, S);
      k_s2<<<dim3(128, Hc), 256, 0, stream>>>(qhi, qlo, k2hi, k2lo, S, attn);
      k_av1<<<dim3(128, Hc), 256, 0, stream>>>(attn, v1T, out1);
      k_av2<<<dim3(128, Hc), 256, 0, stream>>>(attn, v2T, out1, flag, d_out, b, h0);
    }
  }
}